// Round 3
// baseline (279.608 us; speedup 1.0000x reference)
//
#include <hip/hip_runtime.h>

#define BATCH 8192
#define NCOL  4096
#define BLOCK 512
#define NWAVE (BLOCK / 64)        // 8 waves
#define CHUNK (NCOL / BLOCK)      // 8 elements per thread
#define GRID  1024
#define RPB   (BATCH / GRID)      // 8 rows per block

__global__ __launch_bounds__(BLOCK) void listmle_main(
        const float* __restrict__ outputs,
        const int*   __restrict__ labels,
        double*      __restrict__ partial) {
    __shared__ float row[NCOL];       // staged outputs row (16 KB)
    __shared__ float wmax[NWAVE];     // per-wave max of staged row
    __shared__ float wtot[NWAVE];     // per-wave scan totals (linear domain)
    __shared__ double wacc[NWAVE];    // final block reduction

    const int t    = threadIdx.x;
    const int lane = t & 63;
    const int wid  = t >> 6;

    float4 v0, v1;                    // next row's values (prefetch buffer)
    int4  lcur0, lcur1;               // current row's labels
    int4  lnext0, lnext1;             // next row's labels

    // ---- prologue: load row 0 ----
    {
        const size_t base = (size_t)blockIdx.x * NCOL;
        const float4* o4 = (const float4*)(outputs + base);
        const int4*   l4 = (const int4*)(labels + base);
        v0 = o4[t];  v1 = o4[BLOCK + t];
        lcur0 = l4[2 * t];  lcur1 = l4[2 * t + 1];
    }
    // stage row 0, row stats
    float sum_out_next;
    {
        float4* r4 = (float4*)row;
        r4[t] = v0;  r4[BLOCK + t] = v1;
        sum_out_next = (v0.x + v0.y) + (v0.z + v0.w)
                     + (v1.x + v1.y) + (v1.z + v1.w);
        float m = fmaxf(fmaxf(fmaxf(v0.x, v0.y), fmaxf(v0.z, v0.w)),
                        fmaxf(fmaxf(v1.x, v1.y), fmaxf(v1.z, v1.w)));
#pragma unroll
        for (int off = 32; off; off >>= 1)
            m = fmaxf(m, __shfl_xor(m, off, 64));
        if (lane == 0) wmax[wid] = m;
    }
    // prefetch row 1
    {
        const size_t base = (size_t)(blockIdx.x + GRID) * NCOL;
        const float4* o4 = (const float4*)(outputs + base);
        const int4*   l4 = (const int4*)(labels + base);
        v0 = o4[t];  v1 = o4[BLOCK + t];
        lnext0 = l4[2 * t];  lnext1 = l4[2 * t + 1];
    }
    __syncthreads();

    float acc = 0.f;
    float sum_out;

    for (int it = 0; it < RPB; ++it) {
        sum_out = sum_out_next;

        // ---- a: row max (broadcast reads) ----
        float M = fmaxf(fmaxf(fmaxf(wmax[0], wmax[1]), fmaxf(wmax[2], wmax[3])),
                        fmaxf(fmaxf(wmax[4], wmax[5]), fmaxf(wmax[6], wmax[7])));

        // ---- b: gather own 8 elems, shifted exps, local prefix ----
        float g[CHUNK];
        g[0] = row[lcur0.x]; g[1] = row[lcur0.y];
        g[2] = row[lcur0.z]; g[3] = row[lcur0.w];
        g[4] = row[lcur1.x]; g[5] = row[lcur1.y];
        g[6] = row[lcur1.z]; g[7] = row[lcur1.w];

        float s[CHUNK];
        float run = 0.f;
#pragma unroll
        for (int i = 0; i < CHUNK; ++i) {
            run += __expf(g[i] - M);
            s[i] = run;
        }

        // ---- c: additive wave scan of chunk totals ----
        float p = run;
#pragma unroll
        for (int off = 1; off < 64; off <<= 1) {
            float o = __shfl_up(p, off, 64);
            if (lane >= off) p += o;
        }
        if (lane == 63) wtot[wid] = p;
        float ep = __shfl_up(p, 1, 64);   // exclusive lane prefix
        if (lane == 0) ep = 0.f;

        __syncthreads();   // B2: row[] / wmax reads done; wtot visible

        // ---- e: stage next row, prefetch row after ----
        if (it + 1 < RPB) {
            float4* r4 = (float4*)row;
            r4[t] = v0;  r4[BLOCK + t] = v1;
            sum_out_next = (v0.x + v0.y) + (v0.z + v0.w)
                         + (v1.x + v1.y) + (v1.z + v1.w);
            float m = fmaxf(fmaxf(fmaxf(v0.x, v0.y), fmaxf(v0.z, v0.w)),
                            fmaxf(fmaxf(v1.x, v1.y), fmaxf(v1.z, v1.w)));
#pragma unroll
            for (int off = 32; off; off >>= 1)
                m = fmaxf(m, __shfl_xor(m, off, 64));
            if (lane == 0) wmax[wid] = m;

            lcur0 = lnext0;  lcur1 = lnext1;
            if (it + 2 < RPB) {
                const size_t base =
                    (size_t)(blockIdx.x + (size_t)(it + 2) * GRID) * NCOL;
                const float4* o4 = (const float4*)(outputs + base);
                const int4*   l4 = (const int4*)(labels + base);
                v0 = o4[t];  v1 = o4[BLOCK + t];
                lnext0 = l4[2 * t];  lnext1 = l4[2 * t + 1];
            }
        }

        // ---- f: full exclusive prefix, scores, accumulate ----
        float P = ep;
#pragma unroll
        for (int w = 0; w < NWAVE - 1; ++w)
            if (w < wid) P += wtot[w];

        // ssum = CHUNK*M + log(prod(P+s_j)); split into 2 products of 4
        float pr0 = (P + s[0]) * (P + s[1]) * (P + s[2]) * (P + s[3]);
        float pr1 = (P + s[4]) * (P + s[5]) * (P + s[6]) * (P + s[7]);
        float ssum = (float)CHUNK * M + __logf(pr0) + __logf(pr1);

        acc += ssum - sum_out;

        __syncthreads();   // B3: staged row k+1 visible; wtot safe for reuse
    }

    // ---- epilogue: block reduction ----
#pragma unroll
    for (int off = 32; off; off >>= 1) acc += __shfl_down(acc, off, 64);
    if (lane == 0) wacc[wid] = (double)acc;
    __syncthreads();
    if (t == 0) {
        double tot = 0.0;
#pragma unroll
        for (int w = 0; w < NWAVE; ++w) tot += wacc[w];
        partial[blockIdx.x] = tot;
    }
}

__global__ __launch_bounds__(256) void listmle_reduce(
        const double* __restrict__ partial, float* __restrict__ out) {
    __shared__ double sh[4];
    double s = 0.0;
    for (int i = threadIdx.x; i < GRID; i += 256) s += partial[i];
#pragma unroll
    for (int off = 32; off; off >>= 1) s += __shfl_down(s, off, 64);
    const int lane = threadIdx.x & 63, wid = threadIdx.x >> 6;
    if (lane == 0) sh[wid] = s;
    __syncthreads();
    if (threadIdx.x == 0) {
        double tot = (sh[0] + sh[1]) + (sh[2] + sh[3]);
        out[0] = (float)(tot * (1.0 / ((double)BATCH * (double)NCOL)));
    }
}

extern "C" void kernel_launch(void* const* d_in, const int* in_sizes, int n_in,
                              void* d_out, int out_size, void* d_ws, size_t ws_size,
                              hipStream_t stream) {
    const float* outputs = (const float*)d_in[0];
    const int*   labels  = (const int*)d_in[1];
    double* partial = (double*)d_ws;    // GRID doubles = 8 KB scratch
    float*  out     = (float*)d_out;

    listmle_main<<<GRID, BLOCK, 0, stream>>>(outputs, labels, partial);
    listmle_reduce<<<1, 256, 0, stream>>>(partial, out);
}